// Round 9
// baseline (207.194 us; speedup 1.0000x reference)
//
#include <hip/hip_runtime.h>
#include <math.h>

// Problem constants
#define Bsz 32
#define Nn  4096
#define DU  64
#define Dm  128

#define GRID_MLP 1024   // 8 tiles (128 rows) per block; 4 blocks/CU resident target
#define BPB 32          // blocks per batch (1024/32)

// workspace layout (float offsets)
#define WS_WKQ 0      // [2][128]  Wk-slice @ q per head
#define WS_BKQ 256    // [2]       bk-slice . q
#define WS_CNT 288    // [32] int  per-batch completion counters   <- memset 0
#define WS_A   320    // [32][2]   sum of alpha                    <- memset 0
#define WS_S   384    // [32][2][128] sum alpha*z                  <- memset 0
#define WS_WP  8576   // packed bf16 MFMA B-fragments: 48 frags * 64 lanes * 8 ushort

#define H1STR 136     // shorts per h1 LDS row (128 + 8 pad), 16B-aligned

typedef short frag_ab __attribute__((ext_vector_type(8)));
typedef float frag_cd __attribute__((ext_vector_type(4)));

__device__ __forceinline__ unsigned short f2bf(float x) {   // RNE (R6's RTZ cost 4x absmax)
    union { float f; unsigned int u; } c; c.f = x;
    unsigned int r = c.u + 0x7fffu + ((c.u >> 16) & 1u);
    return (unsigned short)(r >> 16);
}

// gelu(x) = x * sigmoid(2y) (exact identity for tanh-gelu), log2e folded
__device__ __forceinline__ float gelu_fast(float x) {
    float t = x * x;
    float a = x * fmaf(t, -0.1029432f, -2.3022081f);
    float e = __builtin_amdgcn_exp2f(a);
    return x * __builtin_amdgcn_rcpf(1.0f + e);
}

// K0: 13 blocks. 0..11 pack W1/W2 into MFMA B-frag bf16 streams (to ws, stays
// L2-hot for the main kernel); 12 computes qv/wkq/bkq.
__global__ __launch_bounds__(256) void precompute_kernel(
    const float* __restrict__ embed, const float* __restrict__ Wq,
    const float* __restrict__ bq, const float* __restrict__ Wk,
    const float* __restrict__ bk, const float* __restrict__ W1,
    const float* __restrict__ W2, float* __restrict__ ws)
{
    __shared__ float qv[128];
    const int tid = threadIdx.x;
    const int bid = blockIdx.x;

    if (bid < 12) {
        // frag f, lane L (q2=L>>4, n=L&15) holds B[ks*32+q2*8+j][nt*16+n], j=0..7
        const int e = bid * 256 + tid;     // 0..3071
        const int f = e >> 6, L = e & 63;
        const int q2 = L >> 4, n = L & 15;
        const float* src;
        int ks, nt;
        if (f < 16) { src = W1; ks = f >> 3;        nt = f & 7; }
        else        { src = W2; ks = (f - 16) >> 3; nt = (f - 16) & 7; }
        const int kb = ks * 32 + q2 * 8;
        const int c  = nt * 16 + n;
        unsigned int p[4];
        #pragma unroll
        for (int jj = 0; jj < 4; ++jj) {
            unsigned int lo = f2bf(src[(kb + 2 * jj)     * Dm + c]);
            unsigned int hi = f2bf(src[(kb + 2 * jj + 1) * Dm + c]);
            p[jj] = lo | (hi << 16);
        }
        ((uint4*)(ws + WS_WP))[e] = make_uint4(p[0], p[1], p[2], p[3]);
    } else {
        if (tid < 128) {
            float s = bq[tid];
            #pragma unroll 8
            for (int j = 0; j < 128; ++j) s += embed[j] * Wq[j * 128 + tid];
            qv[tid] = s;
        }
        __syncthreads();
        if (tid < 128) {
            float s0 = 0.f, s1 = 0.f;
            #pragma unroll 8
            for (int dh = 0; dh < 64; ++dh) {
                s0 += Wk[tid * 128 + dh]      * qv[dh];
                s1 += Wk[tid * 128 + 64 + dh] * qv[64 + dh];
            }
            ws[WS_WKQ + tid]       = s0;
            ws[WS_WKQ + 128 + tid] = s1;
        }
        if (tid < 2) {
            float s = 0.f;
            for (int dh = 0; dh < 64; ++dh) s += bk[tid * 64 + dh] * qv[tid * 64 + dh];
            ws[WS_BKQ + tid] = s;
        }
    }
}

// K1: bf16-MFMA fused MLP + alpha + S/A pooling + per-batch fused epilogue.
// 1024 blocks x 512 thr (8 waves = 4 pair-tiles); wave-pair N-split as R7.
// LDS = h1 (17.4 KB) + alpha buf (2 KB) ONLY — weights are read as MFMA frags
// straight from the packed L2-hot stream in ws every iteration (same addresses
// for all waves/blocks -> L1/L2 broadcast). Target: VGPR <= 64 (R7 measured 52,
// R8 with prefetch 64) -> 8 waves/SIMD; LDS allows 4+ blocks/CU -> 32 waves/CU,
// 4 independent barrier groups (R8's 1-block/CU barrier serialization removed).
// NO second launch_bounds arg (R3/R6: force-caps VGPRs -> massive spills).
__global__ __launch_bounds__(512) void mlp_pool_kernel(
    const float* __restrict__ u,  const float* __restrict__ b1,
    const float* __restrict__ b2, const float* __restrict__ Wv,
    const float* __restrict__ bv, const float* __restrict__ Wo,
    const float* __restrict__ bo, float* __restrict__ ws,
    float* __restrict__ out)
{
    __shared__ short lds_h1[4 * 16 * H1STR];   // 4 pair tiles x 16 x 136 bf16 (17.4 KB)
    __shared__ float a2buf[4][16][2][2];       // [pair][row][head][half] (2 KB)
    __shared__ int   do_epi;

    const int tid  = threadIdx.x;
    const int wave = tid >> 6;
    const int lane = tid & 63;
    const int quad = lane >> 4;
    const int n15  = lane & 15;
    const int p    = wave >> 1;     // tile pair 0..3
    const int hf   = wave & 1;      // column half

    // weight fragment stream (global, L2-hot): frag f at wst + f*512 + lane*8
    const short* wst = (const short*)(ws + WS_WP) + lane * 8;

    // per-lane constants for this wave's column half
    float b1c[4], b2c[4], wkq0[4], wkq1[4];
    #pragma unroll
    for (int nt = 0; nt < 4; ++nt) {
        const int c = hf * 64 + nt * 16 + n15;
        b1c[nt]  = b1[c];
        b2c[nt]  = b2[c];
        wkq0[nt] = ws[WS_WKQ + c];
        wkq1[nt] = ws[WS_WKQ + 128 + c];
    }
    const float bkq0 = ws[WS_BKQ];
    const float bkq1 = ws[WS_BKQ + 1];

    const int bb = blockIdx.x >> 5;          // batch
    const int jb = blockIdx.x & 31;          // 128-row chunk within batch
    short* h1t = lds_h1 + p * 16 * H1STR;    // pair-shared tile

    float s0p[4], s1p[4];
    #pragma unroll
    for (int nt = 0; nt < 4; ++nt) { s0p[nt] = 0.f; s1p[nt] = 0.f; }
    float aA0 = 0.f, aA1 = 0.f;

    // prefetch u for iter 0: lane (quad,n15) = row n15 of pair tile, k quad*8..+8, +32
    const float* ub = u + ((size_t)(bb * Nn + jb * 128 + p * 16 + n15)) * DU + quad * 8;
    float4 f0 = *(const float4*)(ub);
    float4 f1 = *(const float4*)(ub + 4);
    float4 f2 = *(const float4*)(ub + 32);
    float4 f3 = *(const float4*)(ub + 36);

    #pragma unroll 1            // keep rolled (full unroll spilled in R2)
    for (int it = 0; it < 2; ++it) {
        frag_ab a0, a1;
        a0[0] = (short)f2bf(f0.x); a0[1] = (short)f2bf(f0.y);
        a0[2] = (short)f2bf(f0.z); a0[3] = (short)f2bf(f0.w);
        a0[4] = (short)f2bf(f1.x); a0[5] = (short)f2bf(f1.y);
        a0[6] = (short)f2bf(f1.z); a0[7] = (short)f2bf(f1.w);
        a1[0] = (short)f2bf(f2.x); a1[1] = (short)f2bf(f2.y);
        a1[2] = (short)f2bf(f2.z); a1[3] = (short)f2bf(f2.w);
        a1[4] = (short)f2bf(f3.x); a1[5] = (short)f2bf(f3.y);
        a1[6] = (short)f2bf(f3.z); a1[7] = (short)f2bf(f3.w);

        // prefetch next iter's u (in flight across both MFMA layers)
        if (it < 1) {
            const float* un = ub + (size_t)(64 * DU);
            f0 = *(const float4*)(un);
            f1 = *(const float4*)(un + 4);
            f2 = *(const float4*)(un + 32);
            f3 = *(const float4*)(un + 36);
        }

        // ---- layer 1 (this half's 64 cols): M16 N64 K64, B frags from global L2
        frag_cd acc[4];
        #pragma unroll
        for (int nt = 0; nt < 4; ++nt) acc[nt] = (frag_cd){0.f, 0.f, 0.f, 0.f};
        #pragma unroll
        for (int nt = 0; nt < 4; ++nt) {
            const int f = hf * 4 + nt;
            frag_ab w0 = *(const frag_ab*)(wst + (f)     * 512);
            acc[nt] = __builtin_amdgcn_mfma_f32_16x16x32_bf16(a0, w0, acc[nt], 0, 0, 0);
            frag_ab w1 = *(const frag_ab*)(wst + (8 + f) * 512);
            acc[nt] = __builtin_amdgcn_mfma_f32_16x16x32_bf16(a1, w1, acc[nt], 0, 0, 0);
        }

        // bias + gelu -> h1 bf16 (RNE) into pair-shared LDS tile
        // D layout: row = quad*4+r, col = hf*64 + nt*16 + n15
        #pragma unroll
        for (int nt = 0; nt < 4; ++nt) {
            #pragma unroll
            for (int r = 0; r < 4; ++r) {
                float g = gelu_fast(acc[nt][r] + b1c[nt]);
                h1t[(quad * 4 + r) * H1STR + hf * 64 + nt * 16 + n15] = (short)f2bf(g);
            }
        }
        __syncthreads();    // B1: both halves' h1 visible

        // ---- layer 2 (this half's 64 cols): M16 N64 K128, B frags from global L2
        frag_cd acc2[4];
        #pragma unroll
        for (int nt = 0; nt < 4; ++nt) acc2[nt] = (frag_cd){0.f, 0.f, 0.f, 0.f};
        #pragma unroll
        for (int ks = 0; ks < 4; ++ks) {
            frag_ab a2 = *(const frag_ab*)&h1t[n15 * H1STR + ks * 32 + quad * 8];
            #pragma unroll
            for (int nt = 0; nt < 4; ++nt) {
                frag_ab w2f = *(const frag_ab*)(wst + (16 + ks * 8 + hf * 4 + nt) * 512);
                acc2[nt] = __builtin_amdgcn_mfma_f32_16x16x32_bf16(a2, w2f, acc2[nt], 0, 0, 0);
            }
        }

        // bias + gelu -> z (this half) fp32 in registers
        #pragma unroll
        for (int nt = 0; nt < 4; ++nt) {
            #pragma unroll
            for (int r = 0; r < 4; ++r)
                acc2[nt][r] = gelu_fast(acc2[nt][r] + b2c[nt]);
        }

        // ---- half-alpha dots, reduce over n15 lanes, publish to a2buf
        float p0[4], p1[4];
        #pragma unroll
        for (int r = 0; r < 4; ++r) { p0[r] = 0.f; p1[r] = 0.f; }
        #pragma unroll
        for (int nt = 0; nt < 4; ++nt) {
            #pragma unroll
            for (int r = 0; r < 4; ++r) {
                p0[r] += acc2[nt][r] * wkq0[nt];
                p1[r] += acc2[nt][r] * wkq1[nt];
            }
        }
        #pragma unroll
        for (int r = 0; r < 4; ++r) {
            #pragma unroll
            for (int d = 1; d < 16; d <<= 1) {
                p0[r] += __shfl_xor(p0[r], d);
                p1[r] += __shfl_xor(p1[r], d);
            }
        }
        if (n15 == 0) {
            #pragma unroll
            for (int r = 0; r < 4; ++r) {
                const int row = quad * 4 + r;
                a2buf[p][row][0][hf] = p0[r];
                a2buf[p][row][1][hf] = p1[r];
            }
        }
        __syncthreads();    // B2: alpha halves visible (also protects h1/a2buf reuse)

        // ---- full alpha for my rows; accumulate S (my cols, z still in acc2) and A
        #pragma unroll
        for (int r = 0; r < 4; ++r) {
            const int row = quad * 4 + r;
            const float al0 = a2buf[p][row][0][0] + a2buf[p][row][0][1] + bkq0;
            const float al1 = a2buf[p][row][1][0] + a2buf[p][row][1][1] + bkq1;
            #pragma unroll
            for (int nt = 0; nt < 4; ++nt) {
                s0p[nt] += al0 * acc2[nt][r];
                s1p[nt] += al1 * acc2[nt][r];
            }
            aA0 += al0; aA1 += al1;
        }
    }

    // cross-quad reduce (quads hold disjoint rows), one atomic batch per wave
    #pragma unroll
    for (int nt = 0; nt < 4; ++nt) {
        s0p[nt] += __shfl_xor(s0p[nt], 16); s0p[nt] += __shfl_xor(s0p[nt], 32);
        s1p[nt] += __shfl_xor(s1p[nt], 16); s1p[nt] += __shfl_xor(s1p[nt], 32);
    }
    aA0 += __shfl_xor(aA0, 16); aA0 += __shfl_xor(aA0, 32);
    aA1 += __shfl_xor(aA1, 16); aA1 += __shfl_xor(aA1, 32);

    if (quad == 0) {
        #pragma unroll
        for (int nt = 0; nt < 4; ++nt) {
            const int c = hf * 64 + nt * 16 + n15;
            atomicAdd(&ws[WS_S + (bb * 2 + 0) * 128 + c], s0p[nt]);
            atomicAdd(&ws[WS_S + (bb * 2 + 1) * 128 + c], s1p[nt]);
        }
    }
    if (hf == 0 && lane == 0) {     // both halves hold identical alpha sums; count once
        atomicAdd(&ws[WS_A + bb * 2 + 0], aA0);
        atomicAdd(&ws[WS_A + bb * 2 + 1], aA1);
    }

    // ---- per-batch completion counter; 32nd finisher runs this batch's epilogue
    __syncthreads();
    if (tid == 0) {
        __threadfence();
        int old = atomicAdd((int*)ws + WS_CNT + bb, 1);
        do_epi = (old == BPB - 1) ? 1 : 0;
    }
    __syncthreads();

    if (do_epi) {
        // reuse lds_h1 as float scratch: sS[256], sA[2], pooled[128], part[512]
        float* eb     = (float*)lds_h1;
        float* e_sS   = eb;
        float* e_sA   = eb + 256;
        float* e_pool = eb + 264;
        float* e_part = eb + 392;

        if (tid < 256) e_sS[tid] = atomicAdd(&ws[WS_S + bb * 256 + tid], 0.f);
        if (tid < 2)   e_sA[tid] = atomicAdd(&ws[WS_A + bb * 2 + tid], 0.f);
        __syncthreads();

        const int i = tid & 127, seg = tid >> 7;      // 4-way split-K over 512 thr
        const int h = i >> 6;
        {
            float dot = 0.f;
            #pragma unroll 8
            for (int d0 = 0; d0 < 32; ++d0) {
                const int d = seg * 32 + d0;
                dot += e_sS[h * 128 + d] * Wv[d * 128 + i];
            }
            e_part[tid] = dot;
        }
        __syncthreads();
        if (tid < 128)
            e_pool[i] = (e_part[i] + e_part[128 + i] + e_part[256 + i] + e_part[384 + i]
                         + e_sA[h] * bv[i]) * (1.0f / 4096.0f);
        __syncthreads();

        {
            float o = 0.f;
            #pragma unroll 8
            for (int d0 = 0; d0 < 32; ++d0) {
                const int d = seg * 32 + d0;
                o += e_pool[d] * Wo[d * 128 + i];
            }
            e_part[tid] = o;
        }
        __syncthreads();
        if (tid < 128)
            out[bb * 128 + i] = bo[i] + e_part[i] + e_part[128 + i] + e_part[256 + i] + e_part[384 + i];
    }
}

extern "C" void kernel_launch(void* const* d_in, const int* in_sizes, int n_in,
                              void* d_out, int out_size, void* d_ws, size_t ws_size,
                              hipStream_t stream) {
    const float* u     = (const float*)d_in[0];
    // d_in[1] = x : unused by the reference
    const float* W1    = (const float*)d_in[2];
    const float* b1    = (const float*)d_in[3];
    const float* W2    = (const float*)d_in[4];
    const float* b2    = (const float*)d_in[5];
    const float* embed = (const float*)d_in[6];
    const float* Wq    = (const float*)d_in[7];
    const float* bq    = (const float*)d_in[8];
    const float* Wk    = (const float*)d_in[9];
    const float* bk    = (const float*)d_in[10];
    const float* Wv    = (const float*)d_in[11];
    const float* bv    = (const float*)d_in[12];
    const float* Wo    = (const float*)d_in[13];
    const float* bo    = (const float*)d_in[14];
    float* ws  = (float*)d_ws;
    float* out = (float*)d_out;

    // zero CNT + A + S
    hipMemsetAsync((char*)d_ws + WS_CNT * 4, 0, (WS_WP - WS_CNT) * 4, stream);
    hipLaunchKernelGGL(precompute_kernel, dim3(13), dim3(256), 0, stream,
                       embed, Wq, bq, Wk, bk, W1, W2, ws);
    hipLaunchKernelGGL(mlp_pool_kernel, dim3(GRID_MLP), dim3(512), 0, stream,
                       u, b1, b2, Wv, bv, Wo, bo, ws, out);
}

// Round 10
// 147.905 us; speedup vs baseline: 1.4009x; 1.4009x over previous
//
#include <hip/hip_runtime.h>
#include <math.h>

// Problem constants
#define Bsz 32
#define Nn  4096
#define DU  64
#define Dm  128

#define GRID_MLP 512    // 2 blocks/CU (66.5 KB LDS each); 8 waves = 4 pair-tiles per block
#define BPB 16          // blocks per batch (512/32); 256 rows per block = 4 iters x 64 rows

// workspace layout (float offsets)
#define WS_WKQ 0      // [2][128]  Wk-slice @ q per head
#define WS_BKQ 256    // [2]       bk-slice . q
#define WS_CNT 288    // [32] int  per-batch completion counters   <- zeroed by K0
#define WS_A   320    // [32][2]   sum of alpha                    <- zeroed by K0
#define WS_S   384    // [32][2][128] sum alpha*z                  <- zeroed by K0
#define WS_WP  8576   // packed bf16 MFMA B-fragments: 48 frags * 64 lanes * 8 ushort

#define H1STR 136     // shorts per h1 LDS row (128 + 8 pad), 16B-aligned

typedef short frag_ab __attribute__((ext_vector_type(8)));
typedef float frag_cd __attribute__((ext_vector_type(4)));

__device__ __forceinline__ unsigned short f2bf(float x) {   // RNE (R6's RTZ cost 4x absmax)
    union { float f; unsigned int u; } c; c.f = x;
    unsigned int r = c.u + 0x7fffu + ((c.u >> 16) & 1u);
    return (unsigned short)(r >> 16);
}

// gelu(x) = x * sigmoid(2y) (exact identity for tanh-gelu), log2e folded
__device__ __forceinline__ float gelu_fast(float x) {
    float t = x * x;
    float a = x * fmaf(t, -0.1029432f, -2.3022081f);
    float e = __builtin_amdgcn_exp2f(a);
    return x * __builtin_amdgcn_rcpf(1.0f + e);
}

// K0: 14 blocks. 0..11 pack W1/W2 into MFMA B-frag bf16 streams (stay L2-hot);
// 12 computes qv/wkq/bkq; 13 zeroes CNT/A/S (replaces the memset dispatch).
__global__ __launch_bounds__(256) void precompute_kernel(
    const float* __restrict__ embed, const float* __restrict__ Wq,
    const float* __restrict__ bq, const float* __restrict__ Wk,
    const float* __restrict__ bk, const float* __restrict__ W1,
    const float* __restrict__ W2, float* __restrict__ ws)
{
    __shared__ float qv[128];
    const int tid = threadIdx.x;
    const int bid = blockIdx.x;

    if (bid < 12) {
        // frag f, lane L (q2=L>>4, n=L&15) holds B[ks*32+q2*8+j][nt*16+n], j=0..7
        const int e = bid * 256 + tid;     // 0..3071
        const int f = e >> 6, L = e & 63;
        const int q2 = L >> 4, n = L & 15;
        const float* src;
        int ks, nt;
        if (f < 16) { src = W1; ks = f >> 3;        nt = f & 7; }
        else        { src = W2; ks = (f - 16) >> 3; nt = (f - 16) & 7; }
        const int kb = ks * 32 + q2 * 8;
        const int c  = nt * 16 + n;
        unsigned int p[4];
        #pragma unroll
        for (int jj = 0; jj < 4; ++jj) {
            unsigned int lo = f2bf(src[(kb + 2 * jj)     * Dm + c]);
            unsigned int hi = f2bf(src[(kb + 2 * jj + 1) * Dm + c]);
            p[jj] = lo | (hi << 16);
        }
        ((uint4*)(ws + WS_WP))[e] = make_uint4(p[0], p[1], p[2], p[3]);
    } else if (bid == 12) {
        if (tid < 128) {
            float s = bq[tid];
            #pragma unroll 8
            for (int j = 0; j < 128; ++j) s += embed[j] * Wq[j * 128 + tid];
            qv[tid] = s;
        }
        __syncthreads();
        if (tid < 128) {
            float s0 = 0.f, s1 = 0.f;
            #pragma unroll 8
            for (int dh = 0; dh < 64; ++dh) {
                s0 += Wk[tid * 128 + dh]      * qv[dh];
                s1 += Wk[tid * 128 + 64 + dh] * qv[64 + dh];
            }
            ws[WS_WKQ + tid]       = s0;
            ws[WS_WKQ + 128 + tid] = s1;
        }
        if (tid < 2) {
            float s = 0.f;
            for (int dh = 0; dh < 64; ++dh) s += bk[tid * 64 + dh] * qv[tid * 64 + dh];
            ws[WS_BKQ + tid] = s;
        }
    } else {
        for (int idx = WS_CNT + tid; idx < WS_WP; idx += 256) ws[idx] = 0.f;
    }
}

// K1: bf16-MFMA fused MLP + alpha + S/A pooling + per-batch fused epilogue.
// 512 blocks x 512 thr (8 waves = 4 pair-tiles); wave-pair N-split as R7.
// LDS 66.5 KB -> 2 blocks/CU = 2 INDEPENDENT barrier domains (R7's 1-block/CU
// stalled the whole CU at each __syncthreads). Weights in LDS (R9: global
// weights miss L1 [48KB>32KB] -> L2 latency on every MFMA, 2x regression).
// NO second launch_bounds arg (R3/R6: force-caps VGPRs -> massive spills);
// VGPR must land <=128 for 4 waves/SIMD (R9 measured 80 with same state).
__global__ __launch_bounds__(512) void mlp_pool_kernel(
    const float* __restrict__ u,  const float* __restrict__ b1,
    const float* __restrict__ b2, const float* __restrict__ Wv,
    const float* __restrict__ bv, const float* __restrict__ Wo,
    const float* __restrict__ bo, float* __restrict__ ws,
    float* __restrict__ out)
{
    __shared__ short lds_w[48 * 512];          // 48 KB weight fragments (both layers)
    __shared__ short lds_h1[4 * 16 * H1STR];   // 4 pair tiles x 16 x 136 bf16 (17.4 KB)
    __shared__ float a2buf[4][16][2][2];       // [pair][row][head][half] (1 KB)
    __shared__ int   do_epi;

    const int tid  = threadIdx.x;
    const int wave = tid >> 6;
    const int lane = tid & 63;
    const int quad = lane >> 4;
    const int n15  = lane & 15;
    const int p    = wave >> 1;     // tile pair 0..3
    const int hf   = wave & 1;      // column half

    // stage all weight fragments global(L2) -> LDS (48 KB, 6 float4/thread)
    {
        const float4* src = (const float4*)(ws + WS_WP);
        float4* dst = (float4*)lds_w;
        #pragma unroll
        for (int i = 0; i < 6; ++i) dst[tid + 512 * i] = src[tid + 512 * i];
    }

    // per-lane constants for this wave's column half
    float b1c[4], b2c[4], wkq0[4], wkq1[4];
    #pragma unroll
    for (int nt = 0; nt < 4; ++nt) {
        const int c = hf * 64 + nt * 16 + n15;
        b1c[nt]  = b1[c];
        b2c[nt]  = b2[c];
        wkq0[nt] = ws[WS_WKQ + c];
        wkq1[nt] = ws[WS_WKQ + 128 + c];
    }
    const float bkq0 = ws[WS_BKQ];
    const float bkq1 = ws[WS_BKQ + 1];
    __syncthreads();

    const int bb = blockIdx.x >> 4;          // batch
    const int jb = blockIdx.x & 15;          // 256-row chunk within batch
    short* h1t = lds_h1 + p * 16 * H1STR;    // pair-shared tile

    float s0p[4], s1p[4];
    #pragma unroll
    for (int nt = 0; nt < 4; ++nt) { s0p[nt] = 0.f; s1p[nt] = 0.f; }
    float aA0 = 0.f, aA1 = 0.f;

    // prefetch u for iter 0: lane (quad,n15) = row n15 of pair tile, k quad*8..+8, +32
    const float* ub = u + ((size_t)(bb * Nn + jb * 256 + p * 16 + n15)) * DU + quad * 8;
    float4 f0 = *(const float4*)(ub);
    float4 f1 = *(const float4*)(ub + 4);
    float4 f2 = *(const float4*)(ub + 32);
    float4 f3 = *(const float4*)(ub + 36);

    #pragma unroll 1            // keep rolled (full unroll spilled in R2)
    for (int it = 0; it < 4; ++it) {
        frag_ab a0, a1;
        a0[0] = (short)f2bf(f0.x); a0[1] = (short)f2bf(f0.y);
        a0[2] = (short)f2bf(f0.z); a0[3] = (short)f2bf(f0.w);
        a0[4] = (short)f2bf(f1.x); a0[5] = (short)f2bf(f1.y);
        a0[6] = (short)f2bf(f1.z); a0[7] = (short)f2bf(f1.w);
        a1[0] = (short)f2bf(f2.x); a1[1] = (short)f2bf(f2.y);
        a1[2] = (short)f2bf(f2.z); a1[3] = (short)f2bf(f2.w);
        a1[4] = (short)f2bf(f3.x); a1[5] = (short)f2bf(f3.y);
        a1[6] = (short)f2bf(f3.z); a1[7] = (short)f2bf(f3.w);

        // prefetch next iter's u (in flight across both MFMA layers)
        if (it < 3) {
            const float* un = ub + (size_t)((it + 1) * 64) * DU;
            f0 = *(const float4*)(un);
            f1 = *(const float4*)(un + 4);
            f2 = *(const float4*)(un + 32);
            f3 = *(const float4*)(un + 36);
        }

        // ---- layer 1 (this half's 64 cols): M16 N64 K64, B from LDS
        frag_cd acc[4];
        #pragma unroll
        for (int nt = 0; nt < 4; ++nt) acc[nt] = (frag_cd){0.f, 0.f, 0.f, 0.f};
        #pragma unroll
        for (int nt = 0; nt < 4; ++nt) {
            const int f = hf * 4 + nt;
            frag_ab w0 = *(const frag_ab*)&lds_w[(f)     * 512 + lane * 8];
            acc[nt] = __builtin_amdgcn_mfma_f32_16x16x32_bf16(a0, w0, acc[nt], 0, 0, 0);
            frag_ab w1 = *(const frag_ab*)&lds_w[(8 + f) * 512 + lane * 8];
            acc[nt] = __builtin_amdgcn_mfma_f32_16x16x32_bf16(a1, w1, acc[nt], 0, 0, 0);
        }

        // bias + gelu -> h1 bf16 (RNE) into pair-shared LDS tile
        // D layout: row = quad*4+r, col = hf*64 + nt*16 + n15
        #pragma unroll
        for (int nt = 0; nt < 4; ++nt) {
            #pragma unroll
            for (int r = 0; r < 4; ++r) {
                float g = gelu_fast(acc[nt][r] + b1c[nt]);
                h1t[(quad * 4 + r) * H1STR + hf * 64 + nt * 16 + n15] = (short)f2bf(g);
            }
        }
        __syncthreads();    // B1: both halves' h1 visible (only 8 waves in this domain)

        // ---- layer 2 (this half's 64 cols): M16 N64 K128, B from LDS
        frag_cd acc2[4];
        #pragma unroll
        for (int nt = 0; nt < 4; ++nt) acc2[nt] = (frag_cd){0.f, 0.f, 0.f, 0.f};
        #pragma unroll
        for (int ks = 0; ks < 4; ++ks) {
            frag_ab a2 = *(const frag_ab*)&h1t[n15 * H1STR + ks * 32 + quad * 8];
            #pragma unroll
            for (int nt = 0; nt < 4; ++nt) {
                frag_ab w2f = *(const frag_ab*)&lds_w[(16 + ks * 8 + hf * 4 + nt) * 512 + lane * 8];
                acc2[nt] = __builtin_amdgcn_mfma_f32_16x16x32_bf16(a2, w2f, acc2[nt], 0, 0, 0);
            }
        }

        // bias + gelu -> z (this half) fp32 in registers
        #pragma unroll
        for (int nt = 0; nt < 4; ++nt) {
            #pragma unroll
            for (int r = 0; r < 4; ++r)
                acc2[nt][r] = gelu_fast(acc2[nt][r] + b2c[nt]);
        }

        // ---- half-alpha dots, reduce over n15 lanes, publish to a2buf
        float p0[4], p1[4];
        #pragma unroll
        for (int r = 0; r < 4; ++r) { p0[r] = 0.f; p1[r] = 0.f; }
        #pragma unroll
        for (int nt = 0; nt < 4; ++nt) {
            #pragma unroll
            for (int r = 0; r < 4; ++r) {
                p0[r] += acc2[nt][r] * wkq0[nt];
                p1[r] += acc2[nt][r] * wkq1[nt];
            }
        }
        #pragma unroll
        for (int r = 0; r < 4; ++r) {
            #pragma unroll
            for (int d = 1; d < 16; d <<= 1) {
                p0[r] += __shfl_xor(p0[r], d);
                p1[r] += __shfl_xor(p1[r], d);
            }
        }
        if (n15 == 0) {
            #pragma unroll
            for (int r = 0; r < 4; ++r) {
                const int row = quad * 4 + r;
                a2buf[p][row][0][hf] = p0[r];
                a2buf[p][row][1][hf] = p1[r];
            }
        }
        __syncthreads();    // B2: alpha halves visible (also protects h1/a2buf reuse)

        // ---- full alpha for my rows; accumulate S (my cols, z in acc2) and A
        #pragma unroll
        for (int r = 0; r < 4; ++r) {
            const int row = quad * 4 + r;
            const float al0 = a2buf[p][row][0][0] + a2buf[p][row][0][1] + bkq0;
            const float al1 = a2buf[p][row][1][0] + a2buf[p][row][1][1] + bkq1;
            #pragma unroll
            for (int nt = 0; nt < 4; ++nt) {
                s0p[nt] += al0 * acc2[nt][r];
                s1p[nt] += al1 * acc2[nt][r];
            }
            aA0 += al0; aA1 += al1;
        }
    }

    // cross-quad reduce (quads hold disjoint rows), one atomic batch per wave
    #pragma unroll
    for (int nt = 0; nt < 4; ++nt) {
        s0p[nt] += __shfl_xor(s0p[nt], 16); s0p[nt] += __shfl_xor(s0p[nt], 32);
        s1p[nt] += __shfl_xor(s1p[nt], 16); s1p[nt] += __shfl_xor(s1p[nt], 32);
    }
    aA0 += __shfl_xor(aA0, 16); aA0 += __shfl_xor(aA0, 32);
    aA1 += __shfl_xor(aA1, 16); aA1 += __shfl_xor(aA1, 32);

    if (quad == 0) {
        #pragma unroll
        for (int nt = 0; nt < 4; ++nt) {
            const int c = hf * 64 + nt * 16 + n15;
            atomicAdd(&ws[WS_S + (bb * 2 + 0) * 128 + c], s0p[nt]);
            atomicAdd(&ws[WS_S + (bb * 2 + 1) * 128 + c], s1p[nt]);
        }
    }
    if (hf == 0 && lane == 0) {     // both halves hold identical alpha sums; count once
        atomicAdd(&ws[WS_A + bb * 2 + 0], aA0);
        atomicAdd(&ws[WS_A + bb * 2 + 1], aA1);
    }

    // ---- per-batch completion counter; 16th finisher runs this batch's epilogue
    __syncthreads();
    if (tid == 0) {
        __threadfence();
        int old = atomicAdd((int*)ws + WS_CNT + bb, 1);
        do_epi = (old == BPB - 1) ? 1 : 0;
    }
    __syncthreads();

    if (do_epi) {
        // reuse lds_h1 as float scratch: sS[256], sA[2], pooled[128], part[512]
        float* eb     = (float*)lds_h1;
        float* e_sS   = eb;
        float* e_sA   = eb + 256;
        float* e_pool = eb + 264;
        float* e_part = eb + 392;

        if (tid < 256) e_sS[tid] = atomicAdd(&ws[WS_S + bb * 256 + tid], 0.f);
        if (tid < 2)   e_sA[tid] = atomicAdd(&ws[WS_A + bb * 2 + tid], 0.f);
        __syncthreads();

        const int i = tid & 127, seg = tid >> 7;      // 4-way split-K over 512 thr
        const int h = i >> 6;
        {
            float dot = 0.f;
            #pragma unroll 8
            for (int d0 = 0; d0 < 32; ++d0) {
                const int d = seg * 32 + d0;
                dot += e_sS[h * 128 + d] * Wv[d * 128 + i];
            }
            e_part[tid] = dot;
        }
        __syncthreads();
        if (tid < 128)
            e_pool[i] = (e_part[i] + e_part[128 + i] + e_part[256 + i] + e_part[384 + i]
                         + e_sA[h] * bv[i]) * (1.0f / 4096.0f);
        __syncthreads();

        {
            float o = 0.f;
            #pragma unroll 8
            for (int d0 = 0; d0 < 32; ++d0) {
                const int d = seg * 32 + d0;
                o += e_pool[d] * Wo[d * 128 + i];
            }
            e_part[tid] = o;
        }
        __syncthreads();
        if (tid < 128)
            out[bb * 128 + i] = bo[i] + e_part[i] + e_part[128 + i] + e_part[256 + i] + e_part[384 + i];
    }
}

extern "C" void kernel_launch(void* const* d_in, const int* in_sizes, int n_in,
                              void* d_out, int out_size, void* d_ws, size_t ws_size,
                              hipStream_t stream) {
    const float* u     = (const float*)d_in[0];
    // d_in[1] = x : unused by the reference
    const float* W1    = (const float*)d_in[2];
    const float* b1    = (const float*)d_in[3];
    const float* W2    = (const float*)d_in[4];
    const float* b2    = (const float*)d_in[5];
    const float* embed = (const float*)d_in[6];
    const float* Wq    = (const float*)d_in[7];
    const float* bq    = (const float*)d_in[8];
    const float* Wk    = (const float*)d_in[9];
    const float* bk    = (const float*)d_in[10];
    const float* Wv    = (const float*)d_in[11];
    const float* bv    = (const float*)d_in[12];
    const float* Wo    = (const float*)d_in[13];
    const float* bo    = (const float*)d_in[14];
    float* ws  = (float*)d_ws;
    float* out = (float*)d_out;

    hipLaunchKernelGGL(precompute_kernel, dim3(14), dim3(256), 0, stream,
                       embed, Wq, bq, Wk, bk, W1, W2, ws);
    hipLaunchKernelGGL(mlp_pool_kernel, dim3(GRID_MLP), dim3(512), 0, stream,
                       u, b1, b2, Wv, bv, Wo, bo, ws, out);
}